// Round 5
// baseline (265.850 us; speedup 1.0000x reference)
//
#include <hip/hip_runtime.h>

// Shapes fixed by the reference: B=64, N=576, C=1024.
#define B_ 64
#define N_ 576
#define C_ 1024
#define ROWS_PER_BLK 8   // 576 % 8 == 0 -> a block never straddles batches

typedef float v4f __attribute__((ext_vector_type(4)));  // native vector for nontemporal builtins

// K1: logits[row] = dot(V[row,:], W[0:C]); one 64-lane wave per TWO rows.
// W fragment (4 x float4 per lane) loaded once, reused for both rows ->
// halves W cache traffic, 8 outstanding V loads per lane.
// Budget-embedding term + bias are constant per b and rank-preserving -> dropped.
__global__ __launch_bounds__(256) void k_logits(const float* __restrict__ V,
                                                const float* __restrict__ W,
                                                float* __restrict__ logits,
                                                int BN) {
    int wave = (int)((blockIdx.x * blockDim.x + threadIdx.x) >> 6);
    int lane = threadIdx.x & 63;
    int row0 = wave * 2;
    if (row0 >= BN) return;
    const v4f* w4 = (const v4f*)W;
    v4f wr[4];
#pragma unroll
    for (int it = 0; it < 4; ++it) wr[it] = w4[lane + it * 64];

    float acc0 = 0.f, acc1 = 0.f;
    const v4f* va = (const v4f*)(V + (size_t)row0 * C_);
    const v4f* vb = (const v4f*)(V + (size_t)(row0 + 1) * C_);
#pragma unroll
    for (int it = 0; it < 4; ++it) {
        v4f a = va[lane + it * 64];
        v4f b = vb[lane + it * 64];
        acc0 += a.x * wr[it].x + a.y * wr[it].y + a.z * wr[it].z + a.w * wr[it].w;
        acc1 += b.x * wr[it].x + b.y * wr[it].y + b.z * wr[it].z + b.w * wr[it].w;
    }
#pragma unroll
    for (int off = 32; off; off >>= 1) {
        acc0 += __shfl_xor(acc0, off, 64);
        acc1 += __shfl_xor(acc1, off, 64);
    }
    if (lane == 0) {
        logits[row0] = acc0;
        logits[row0 + 1] = acc1;
    }
}

// K23: fused mask + scale. Each block owns 8 rows of one batch b.
//  1) stage batch b's 576 logits (L2-resident ws) into LDS
//  2) wave w ranks rows n0+w and n0+4+w (O(N) compares, tie -> lower index,
//     matching jnp.argmax first-occurrence of the iterative gumbel scan);
//     K = clip((int)(budget*N), 1, N)
//  3) mask -> d_out tail + LDS; copy/zero the 8 rows (block-uniform branch;
//     dropped rows skip the V read; nontemporal stores keep the write stream
//     from evicting LLC-resident V).
__global__ __launch_bounds__(256) void k_mask_scale(const float* __restrict__ V,
                                                    const float* __restrict__ logits,
                                                    const float* __restrict__ token_budget,
                                                    float* __restrict__ out_feat,
                                                    float* __restrict__ out_mask) {
    __shared__ float sl[N_];
    __shared__ float smask[ROWS_PER_BLK];
    int row0 = blockIdx.x * ROWS_PER_BLK;
    int b = row0 / N_;
    int n0 = row0 - b * N_;
    int t = threadIdx.x;

    // stage 576 logits (2*256 + 64)
    sl[t] = logits[b * N_ + t];
    sl[t + 256] = logits[b * N_ + t + 256];
    if (t < 64) sl[t + 512] = logits[b * N_ + t + 512];
    __syncthreads();

    int K = (int)(token_budget[b] * (float)N_);  // astype(int32) truncates toward zero
    K = K < 1 ? 1 : (K > N_ ? N_ : K);

    int w = t >> 6, l = t & 63;
#pragma unroll
    for (int rr = 0; rr < 2; ++rr) {
        int widx = w + rr * 4;       // local row slot 0..7
        int n = n0 + widx;           // this wave's row (local index in batch)
        float ln = sl[n];
        int rank = 0;
#pragma unroll
        for (int i = 0; i < N_ / 64; ++i) {  // 9 iters
            int m = l + 64 * i;
            float lm = sl[m];
            rank += (lm > ln) || (lm == ln && m < n);
        }
#pragma unroll
        for (int off = 32; off; off >>= 1) rank += __shfl_xor(rank, off, 64);
        if (l == 0) {
            float mv = (rank < K) ? 1.0f : 0.0f;
            smask[widx] = mv;
            out_mask[b * N_ + n] = mv;
        }
    }
    __syncthreads();

    const v4f z = {0.f, 0.f, 0.f, 0.f};
#pragma unroll
    for (int r = 0; r < ROWS_PER_BLK; ++r) {
        int row = row0 + r;
        float m = smask[r];          // block-uniform
        const v4f* v4 = (const v4f*)(V + (size_t)row * C_);
        v4f* o4 = (v4f*)(out_feat + (size_t)row * C_);
        if (m != 0.0f) {
            v4f v = v4[t];           // C/4 == 256 float4 per row
            __builtin_nontemporal_store(v, &o4[t]);
        } else {
            __builtin_nontemporal_store(z, &o4[t]);
        }
    }
}

extern "C" void kernel_launch(void* const* d_in, const int* in_sizes, int n_in,
                              void* d_out, int out_size, void* d_ws, size_t ws_size,
                              hipStream_t stream) {
    const float* V  = (const float*)d_in[0];  // [B,N,C]
    const float* tb = (const float*)d_in[1];  // [B]
    // d_in[2] (budget_embedding), W[C:2C), bias: per-row rank-preserving constants.
    const float* W  = (const float*)d_in[3];  // [1,2C]

    float* out_feat = (float*)d_out;                         // [B,N,C]
    float* out_mask = (float*)d_out + (size_t)B_ * N_ * C_;  // [B,N]

    float* ws_logits = (float*)d_ws;  // B*N floats

    const int BN = B_ * N_;
    // K1: 2 rows/wave, 4 waves/block -> 8 rows/block
    k_logits<<<(BN + 7) / 8, 256, 0, stream>>>(V, W, ws_logits, BN);
    k_mask_scale<<<BN / ROWS_PER_BLK, 256, 0, stream>>>(V, ws_logits, tb, out_feat, out_mask);
}

// Round 6
// 262.866 us; speedup vs baseline: 1.0113x; 1.0113x over previous
//
#include <hip/hip_runtime.h>

// Shapes fixed by the reference: B=64, N=576, C=1024.
#define B_ 64
#define N_ 576
#define C_ 1024
#define ROWS_PER_BLK 4   // 576 % 4 == 0 -> a block never straddles batches

typedef float v4f __attribute__((ext_vector_type(4)));  // native vector for nontemporal builtins

// K1: logits[b*N+n] = dot(V[b,n,:], W[0:C]); one 64-lane wave per row.
// Budget-embedding term + bias are constant per b and rank-preserving -> dropped.
__global__ __launch_bounds__(256) void k_logits(const float* __restrict__ V,
                                                const float* __restrict__ W,
                                                float* __restrict__ logits,
                                                int BN) {
    int wave = (int)((blockIdx.x * blockDim.x + threadIdx.x) >> 6);
    int lane = threadIdx.x & 63;
    if (wave >= BN) return;
    const v4f* v4 = (const v4f*)(V + (size_t)wave * C_);
    const v4f* w4 = (const v4f*)W;  // only first C floats matter for ranking
    float acc = 0.f;
#pragma unroll
    for (int it = 0; it < C_ / (64 * 4); ++it) {  // 4 iters, full row coalesced
        v4f v = v4[lane + it * 64];
        v4f w = w4[lane + it * 64];
        acc += v.x * w.x + v.y * w.y + v.z * w.z + v.w * w.w;
    }
#pragma unroll
    for (int off = 32; off; off >>= 1) acc += __shfl_xor(acc, off, 64);
    if (lane == 0) logits[wave] = acc;
}

// K23: fused mask + scale. Each block owns 4 rows of one batch b.
//  1) stage batch b's 576 logits from L2-resident ws into LDS
//  2) wave w computes rank of row n0+w (O(N) compares, tie -> lower index,
//     matching jnp.argmax first-occurrence of the iterative gumbel scan);
//     K = clip((int)(budget*N), 1, N)
//  3) mask -> d_out tail + LDS; then copy/zero the 4 rows (block-uniform branch,
//     dropped rows skip the V read entirely; nontemporal stores keep the write
//     stream from evicting LLC-resident V).
__global__ __launch_bounds__(256) void k_mask_scale(const float* __restrict__ V,
                                                    const float* __restrict__ logits,
                                                    const float* __restrict__ token_budget,
                                                    float* __restrict__ out_feat,
                                                    float* __restrict__ out_mask) {
    __shared__ float sl[N_];
    __shared__ float smask[ROWS_PER_BLK];
    int row0 = blockIdx.x * ROWS_PER_BLK;
    int b = row0 / N_;
    int n0 = row0 - b * N_;
    int t = threadIdx.x;

    // stage 576 logits (2*256 + 64)
    sl[t] = logits[b * N_ + t];
    sl[t + 256] = logits[b * N_ + t + 256];
    if (t < 64) sl[t + 512] = logits[b * N_ + t + 512];
    __syncthreads();

    int K = (int)(token_budget[b] * (float)N_);  // astype(int32) truncates toward zero
    K = K < 1 ? 1 : (K > N_ ? N_ : K);

    int w = t >> 6, l = t & 63;
    {
        int n = n0 + w;              // this wave's row (local index in batch)
        float ln = sl[n];
        int rank = 0;
#pragma unroll
        for (int i = 0; i < N_ / 64; ++i) {  // 9 iters
            int m = l + 64 * i;
            float lm = sl[m];
            rank += (lm > ln) || (lm == ln && m < n);
        }
#pragma unroll
        for (int off = 32; off; off >>= 1) rank += __shfl_xor(rank, off, 64);
        if (l == 0) {
            float mv = (rank < K) ? 1.0f : 0.0f;
            smask[w] = mv;
            out_mask[b * N_ + n] = mv;
        }
    }
    __syncthreads();

    const v4f z = {0.f, 0.f, 0.f, 0.f};
#pragma unroll
    for (int r = 0; r < ROWS_PER_BLK; ++r) {
        int row = row0 + r;
        float m = smask[r];          // block-uniform
        const v4f* v4 = (const v4f*)(V + (size_t)row * C_);
        v4f* o4 = (v4f*)(out_feat + (size_t)row * C_);
        if (m != 0.0f) {
            v4f v = v4[t];           // C/4 == 256 float4 per row
            __builtin_nontemporal_store(v, &o4[t]);
        } else {
            __builtin_nontemporal_store(z, &o4[t]);
        }
    }
}

extern "C" void kernel_launch(void* const* d_in, const int* in_sizes, int n_in,
                              void* d_out, int out_size, void* d_ws, size_t ws_size,
                              hipStream_t stream) {
    const float* V  = (const float*)d_in[0];  // [B,N,C]
    const float* tb = (const float*)d_in[1];  // [B]
    // d_in[2] (budget_embedding), W[C:2C), bias: per-row rank-preserving constants.
    const float* W  = (const float*)d_in[3];  // [1,2C]

    float* out_feat = (float*)d_out;                         // [B,N,C]
    float* out_mask = (float*)d_out + (size_t)B_ * N_ * C_;  // [B,N]

    float* ws_logits = (float*)d_ws;  // B*N floats

    const int BN = B_ * N_;
    k_logits<<<(BN + 3) / 4, 256, 0, stream>>>(V, W, ws_logits, BN);
    k_mask_scale<<<BN / ROWS_PER_BLK, 256, 0, stream>>>(V, ws_logits, tb, out_feat, out_mask);
}